// Round 12
// baseline (1429.293 us; speedup 1.0000x reference)
//
#include <hip/hip_runtime.h>
#include <cstdint>
#include <cstddef>

typedef unsigned int u32;
typedef unsigned long long u64;
typedef float vf4 __attribute__((ext_vector_type(4)));

#define NF 300
#define NCLS 80
#define NCLS1 81
#define FH 200
#define FW 200
#define PIX 40000
#define NC 24000
#define KCAND 1000
#define CAP 4096
#define NBINS 65536
#define MAXSEG 100
#define OUT_MASK_OFF 100
#define OUT_SCORE_OFF 104857700
#define OUT_BATCH_OFF 104857800
#define NEG_BIG -3.3895313892515355e38f  /* finite sentinel, != -inf */
#define RYC 16   /* output rows per resize block (r10 variant) */

// ---- PROBE ROUND 4: A/B the two bit-identical resize structures, rep'd x8 each.
// r10 (LDS-staged, barriers) vs r11_gather (no LDS, no barriers, 1 row/block).
// Both write identical bytes -> chain output unchanged. Whichever is faster per
// rep (and why, per its occupancy/BW counters) ships next round. If both ~110us,
// the store path at this shape is the wall -> roofline case.
#define REP_A 8
#define REP_B 8

// workspace byte offsets
#define WS_HIST      0u        // 65536*4
#define WS_KEYS      262144u   // 24000*8
#define WS_COLLECT   454144u   // 4096*8
#define WS_CNT       486912u   // 4*4
#define WS_BOXES     486928u   // 300*16 (16B aligned)
#define WS_CLAB      496928u
#define WS_CFEAT     500928u
#define WS_CSCORE    504928u
#define WS_CBOX      508928u   // 1000*16 (16B aligned)
#define WS_ROWBITS   524928u   // 16*1024*8 TRANSPOSED: word ch, row i -> [ch*1024+i]
#define WS_SELFEAT   656128u   // 100*4

__device__ __forceinline__ u32 ord32_r3(float f) {
  u32 b = __float_as_uint(f);
  return (b & 0x80000000u) ? ~b : (b | 0x80000000u);
}
__device__ __forceinline__ float unord32_r3(u32 o) {
  u32 b = (o & 0x80000000u) ? (o & 0x7FFFFFFFu) : ~o;
  return __uint_as_float(b);
}

// Exact bilinear weight for output index i (1024 -> 200, same both axes).
__device__ __forceinline__ float4 wcalc_r4(int i) {
  float s = __fsub_rn(__fmul_rn((float)i + 0.5f, 0.1953125f), 0.5f);
  int j0 = (int)floorf(s);
  int j1 = j0 + 1;
  float w0 = fmaxf(0.f, __fsub_rn(1.f, fabsf(__fsub_rn(s, (float)j0))));
  float w1 = fmaxf(0.f, __fsub_rn(1.f, fabsf(__fsub_rn(s, (float)j1))));
  bool in0 = (j0 >= 0) && (j0 < FH);
  bool in1 = (j1 >= 0) && (j1 < FH);
  float tot = __fadd_rn(in0 ? w0 : 0.f, in1 ? w1 : 0.f);
  float w0n = in0 ? (w0 / tot) : 0.f;   // IEEE div
  float w1n = in1 ? (w1 / tot) : 0.f;
  return make_float4(w0n, w1n, (float)max(j0, 0), (float)min(j1, FH - 1));
}

// ---------------- A: zero hist + counters ----------------
__global__ void r5_init(u32* __restrict__ hist, u32* __restrict__ cnts) {
  int i = blockIdx.x * 256 + threadIdx.x;   // grid covers 65536
  hist[i] = 0u;
  if (i < 4) cnts[i] = 0u;
}

// ---------------- B: per-mask bbox + fused sigmoid scores/keys + global hist ------
__global__ void r5_boxes(const float* __restrict__ seg, const float* __restrict__ cls,
                         float4* __restrict__ boxes, u64* __restrict__ keys,
                         u32* __restrict__ hist) {
  __shared__ int sminx[256], sminy[256], smaxx[256], smaxy[256];
  int n = blockIdx.x, t = threadIdx.x;
  const float4* img = (const float4*)(seg + (size_t)n * PIX);
  int minx = FW, miny = FH, maxx = -1, maxy = -1;
  for (int q = t; q < PIX / 4; q += 256) {
    float4 v = img[q];
    int p = q * 4;
    int y = p / FW;
    int x = p - y * FW;
    if (v.x > 0.f) { minx = min(minx, x);     maxx = max(maxx, x);     miny = min(miny, y); maxy = max(maxy, y); }
    if (v.y > 0.f) { minx = min(minx, x + 1); maxx = max(maxx, x + 1); miny = min(miny, y); maxy = max(maxy, y); }
    if (v.z > 0.f) { minx = min(minx, x + 2); maxx = max(maxx, x + 2); miny = min(miny, y); maxy = max(maxy, y); }
    if (v.w > 0.f) { minx = min(minx, x + 3); maxx = max(maxx, x + 3); miny = min(miny, y); maxy = max(maxy, y); }
  }
  sminx[t] = minx; sminy[t] = miny; smaxx[t] = maxx; smaxy[t] = maxy;
  __syncthreads();
  for (int s = 128; s > 0; s >>= 1) {
    if (t < s) {
      sminx[t] = min(sminx[t], sminx[t + s]);
      sminy[t] = min(sminy[t], sminy[t + s]);
      smaxx[t] = max(smaxx[t], smaxx[t + s]);
      smaxy[t] = max(smaxy[t], smaxy[t + s]);
    }
    __syncthreads();
  }
  bool ne = smaxx[0] >= 0;
  if (t == 0) {
    float4 b;
    if (ne) b = make_float4((float)sminx[0], (float)sminy[0], (float)(smaxx[0] + 1), (float)(smaxy[0] + 1));
    else    b = make_float4(0.f, 0.f, (float)FW, (float)FH);  // argmax-of-all-false semantics
    boxes[n] = b;
  }
  if (t < NCLS) {
    float sc;
    if (ne) {
      float lg = cls[n * NCLS1 + t];
      sc = 1.0f / (1.0f + expf(-lg));
    } else {
      sc = -1.0f;
    }
    u32 o = ord32_r3(sc);
    u32 i = (u32)(n * NCLS + t);
    keys[i] = ((u64)o << 32) | (u64)(0xFFFFFFFFu - i);  // lower index -> larger key on ties
    atomicAdd(&hist[o >> 16], 1u);
  }
}

// ---------------- C: histogram bin of the 1000th largest key (uint4 loads) --------
__global__ void r6_thresh(const u32* __restrict__ hist, u32* __restrict__ cnts) {
  __shared__ u32 s[1024];
  int t = threadIdx.x;
  const uint4* hp = (const uint4*)(hist) + t * 16;
  u32 sum = 0;
  #pragma unroll
  for (int b = 0; b < 16; b++) {
    uint4 v = hp[b];
    sum += v.x + v.y + v.z + v.w;
  }
  s[t] = sum;
  __syncthreads();
  for (int off = 1; off < 1024; off <<= 1) {
    u32 v = s[t];
    u32 o = (t + off < 1024) ? s[t + off] : 0u;
    __syncthreads();
    s[t] = v + o;
    __syncthreads();
  }
  u32 sufnext = (t < 1023) ? s[t + 1] : 0u;
  if (s[t] >= (u32)KCAND && sufnext < (u32)KCAND) {
    u32 run = sufnext;
    u32 B = (u32)(t * 64);
    for (int b = 63; b >= 0; b--) {
      run += hist[t * 64 + b];
      if (run >= (u32)KCAND) { B = (u32)(t * 64 + b); break; }
    }
    cnts[1] = B;
  }
}

// ---------------- D: collect (wave-aggregated atomic) ----------------
__global__ void r5_collect(const u64* __restrict__ keys, const u32* __restrict__ cnts,
                           u64* __restrict__ collect, u32* __restrict__ counter) {
  int i = blockIdx.x * 256 + threadIdx.x;
  u32 B = cnts[1];
  bool pass = false;
  u64 k = 0ull;
  if (i < NC) {
    k = keys[i];
    pass = ((u32)(k >> 48) >= B);
  }
  u64 m = __ballot(pass);
  int lane = threadIdx.x & 63;
  u32 base = 0u;
  if (lane == 0 && m) base = atomicAdd(counter, (u32)__popcll(m));
  base = __shfl(base, 0, 64);
  if (pass) {
    u32 pos = base + (u32)__popcll(m & ((1ull << lane) - 1ull));
    if (pos < CAP) collect[pos] = k;
  }
}

// ---------------- E: exact stable rank, 16 blocks x 256 --------
__global__ void r5_rank(const u64* __restrict__ collect, const u32* __restrict__ cnts,
                        const float4* __restrict__ boxes,
                        int* __restrict__ clab, int* __restrict__ cfeat,
                        float* __restrict__ cscore, float4* __restrict__ cbox) {
  __shared__ u64 sk[CAP];
  int M = min((int)cnts[0], CAP);
  int t = threadIdx.x;
  for (int j = t; j < M; j += 256) sk[j] = collect[j];
  __syncthreads();
  int j = blockIdx.x * 256 + t;   // 16*256 = 4096 = CAP covers all M
  if (j < M) {
    u64 my = sk[j];
    int r = 0;
    for (int k = 0; k < M; k++) r += (sk[k] > my) ? 1 : 0;
    if (r < KCAND) {
      u32 idx = 0xFFFFFFFFu - (u32)(my & 0xFFFFFFFFull);
      int n = (int)idx / NCLS, c = (int)idx - n * NCLS;
      clab[r] = c;
      cfeat[r] = n;
      cscore[r] = unord32_r3((u32)(my >> 32));
      float4 b = boxes[n];
      float off = (float)c * 201.0f;  // label * (max(fH,fW)+1) on all 4 coords
      cbox[r] = make_float4(b.x + off, b.y + off, b.z + off, b.w + off);
    }
  }
}

// ---------------- F: IoU > thr bitmask rows, TRANSPOSED [word][row] layout --------
__global__ void r7_iou(const float4* __restrict__ cbox, u64* __restrict__ rowT) {
  __shared__ float4 sb[KCAND];
  int t = threadIdx.x;
  for (int j = t; j < KCAND; j += 256) sb[j] = cbox[j];
  __syncthreads();
  int w = t >> 6, lane = t & 63;
  int i = blockIdx.x * 4 + w;     // 256 blocks -> rows 0..1023 (rows >=1000 write 0)
  float4 bi = make_float4(0.f, 0.f, 0.f, 0.f);
  float ai = 0.f;
  if (i < KCAND) { bi = sb[i]; ai = (bi.z - bi.x) * (bi.w - bi.y); }
  for (int ch = 0; ch < 16; ch++) {
    int j = ch * 64 + lane;
    bool pred = false;
    if (i < KCAND && j < KCAND && j > i) {
      float4 bj = sb[j];
      float aj = (bj.z - bj.x) * (bj.w - bj.y);
      float ix1 = fmaxf(bi.x, bj.x), iy1 = fmaxf(bi.y, bj.y);
      float ix2 = fminf(bi.z, bj.z), iy2 = fminf(bi.w, bj.w);
      float inter = fmaxf(ix2 - ix1, 0.f) * fmaxf(iy2 - iy1, 0.f);
      float uni = ai + aj - inter;
      float iou = inter / fmaxf(uni, 1e-9f);
      pred = iou > 0.65f;
    }
    u64 m = __ballot(pred);
    if (lane == 0) rowT[(size_t)ch * 1024 + i] = m;
  }
}

// ---------------- G: greedy NMS scan, wave-parallel propagation + selection -------
__global__ void r7_nms_sel(const u64* __restrict__ rowT, const float* __restrict__ cscore,
                           const int* __restrict__ clab, const int* __restrict__ cfeat,
                           float* __restrict__ out, int* __restrict__ selfeat) {
  __shared__ u64 sup[16];
  __shared__ u64 keep[16];
  __shared__ u64 sel[16];
  __shared__ u32 pre[17];
  int t = threadIdx.x;
  int wv = t >> 6, lane = t & 63;
  if (t < 16) sup[t] = 0ull;
  __syncthreads();
  for (int c = 0; c < 16; c++) {
    u64 row = 0ull;
    if (wv > c) row = rowT[(size_t)wv * 1024 + c * 64 + lane];
    if (wv == 0) {
      u64 r = rowT[(size_t)c * 1024 + c * 64 + lane];  // diag word, coalesced
      u64 s = sup[c];
      u64 k = 0ull;
      #pragma unroll
      for (int b = 0; b < 64; b++) {
        u64 rb = __shfl(r, b, 64);   // constant b -> v_readlane
        if (!((s >> b) & 1ull)) { s |= rb; k |= (1ull << b); }
      }
      if (lane == 0) keep[c] = k;
    }
    __syncthreads();
    if (wv > c) {
      u64 kk = keep[c];
      u64 acc = ((kk >> lane) & 1ull) ? row : 0ull;
      #pragma unroll
      for (int off = 32; off >= 1; off >>= 1) acc |= __shfl_xor(acc, off, 64);
      if (lane == 0) sup[wv] |= acc;
    }
    __syncthreads();
  }
  {
    bool s = false;
    if (t < KCAND) {
      bool kp = ((keep[t >> 6] >> (t & 63)) & 1ull) != 0ull;
      s = kp && (cscore[t] >= 0.f);
    }
    u64 m = __ballot(s);
    if (lane == 0) sel[wv] = m;
  }
  __syncthreads();
  if (t == 0) {
    u32 acc = 0;
    #pragma unroll
    for (int c = 0; c < 16; c++) { pre[c] = acc; acc += (u32)__popcll(sel[c]); }
    pre[16] = acc;
  }
  __syncthreads();
  u32 nkept = pre[16];
  if (t < KCAND) {
    int j = t;
    u64 w = sel[j >> 6];
    bool s = ((w >> (j & 63)) & 1ull) != 0ull;
    u32 below = pre[j >> 6] + (u32)__popcll(w & ((1ull << (j & 63)) - 1ull));
    u32 r = s ? below : (nkept + (u32)j - below);
    if (r < MAXSEG) {
      out[r] = (float)clab[j];
      out[OUT_SCORE_OFF + r] = s ? cscore[j] : NEG_BIG;
      out[OUT_BATCH_OFF + r] = 0.0f;
      selfeat[r] = cfeat[j];
    }
  }
}

// ---------------- R-A: H-then-W LDS-staged resize (round-11 kernel), rep'd -------
__global__ void __launch_bounds__(256, 4) r10_resize(const float* __restrict__ seg,
                                                     const int* __restrict__ selfeat,
                                                     float* __restrict__ outm) {
  __shared__ float srow[6][FW];
  __shared__ float th[RYC][FW];
  __shared__ float4 swy[RYC];
  int t = threadIdx.x;
  int yb = blockIdx.x * RYC, slot = blockIdx.y;
  int feat = selfeat[slot];
  const float* img = seg + (size_t)feat * PIX;
  float4 wxa = wcalc_r4(t * 4), wxb = wcalc_r4(t * 4 + 1),
         wxc = wcalc_r4(t * 4 + 2), wxd = wcalc_r4(t * 4 + 3);
  int ylo = (int)wcalc_r4(yb).z;
  int yhi = (int)wcalc_r4(yb + RYC - 1).w;
  int nr = yhi - ylo + 1;                      // <= 5
  int xa0 = (int)wxa.z, xa1 = (int)wxa.w;
  int xb0 = (int)wxb.z, xb1 = (int)wxb.w;
  int xc0 = (int)wxc.z, xc1 = (int)wxc.w;
  int xd0 = (int)wxd.z, xd1 = (int)wxd.w;
  float* obase = outm + (size_t)slot * 1048576 + (size_t)yb * 1024 + t * 4;
  for (int rep = 0; rep < REP_A; ++rep) {
    __syncthreads();   // protect LDS reuse across reps
    if (t < RYC) {
      float4 wy = wcalc_r4(yb + t);
      swy[t] = make_float4(wy.x, wy.y, (float)((int)wy.z - ylo), (float)((int)wy.w - ylo));
    }
    for (int e = t; e < nr * FW; e += 256) {
      int rr = e / FW, cc = e - rr * FW;
      srow[rr][cc] = img[(ylo + rr) * FW + cc];
    }
    __syncthreads();
    #pragma unroll
    for (int r = 0; r < RYC; ++r) {
      if (t < FW) {
        float4 wy = swy[r];
        th[r][t] = __fmaf_rn(wy.y, srow[(int)wy.w][t], __fmul_rn(wy.x, srow[(int)wy.z][t]));
      }
    }
    __syncthreads();
    #pragma unroll
    for (int r = 0; r < RYC; ++r) {
      const float* thr = th[r];
      float va = __fmaf_rn(wxa.y, thr[xa1], __fmul_rn(wxa.x, thr[xa0]));
      float vb = __fmaf_rn(wxb.y, thr[xb1], __fmul_rn(wxb.x, thr[xb0]));
      float vc = __fmaf_rn(wxc.y, thr[xc1], __fmul_rn(wxc.x, thr[xc0]));
      float vd = __fmaf_rn(wxd.y, thr[xd1], __fmul_rn(wxd.x, thr[xd0]));
      vf4 res;
      res.x = (va > 0.0f) ? 1.0f : 0.0f;
      res.y = (vb > 0.0f) ? 1.0f : 0.0f;
      res.z = (vc > 0.0f) ? 1.0f : 0.0f;
      res.w = (vd > 0.0f) ? 1.0f : 0.0f;
      *(vf4*)(obase + (size_t)r * 1024) = res;
    }
  }
}

// ---------------- R-B: gather resize — no LDS, no barriers, 1 row/block ----------
// Each thread: 4 outputs of one row = 16 L2-hot loads + 12 mul/fma + 1 float4
// store. Same fma order as r4 (H contracted first) -> bit-identical to R-A.
// ~30 VGPR, no LDS -> high occupancy; tests the concurrency hypothesis.
__global__ void __launch_bounds__(256) r11_gather(const float* __restrict__ seg,
                                                  const int* __restrict__ selfeat,
                                                  float* __restrict__ outm) {
  int t = threadIdx.x;
  int row = blockIdx.x;          // output row 0..1023
  int slot = blockIdx.y;
  int feat = selfeat[slot];
  const float* img = seg + (size_t)feat * PIX;
  float4 wy = wcalc_r4(row);
  const float* r0 = img + (int)wy.z * FW;
  const float* r1 = img + (int)wy.w * FW;
  float wy0 = wy.x, wy1 = wy.y;
  float4 wxa = wcalc_r4(t * 4), wxb = wcalc_r4(t * 4 + 1),
         wxc = wcalc_r4(t * 4 + 2), wxd = wcalc_r4(t * 4 + 3);
  int xa0 = (int)wxa.z, xa1 = (int)wxa.w;
  int xb0 = (int)wxb.z, xb1 = (int)wxb.w;
  int xc0 = (int)wxc.z, xc1 = (int)wxc.w;
  int xd0 = (int)wxd.z, xd1 = (int)wxd.w;
  float* optr = outm + (size_t)slot * 1048576 + (size_t)row * 1024 + t * 4;
  for (int rep = 0; rep < REP_B; ++rep) {
    const float* r0r = r0;
    const float* r1r = r1;
    asm volatile("" : "+v"(r0r), "+v"(r1r));   // defeat load hoisting across reps
    float ta0 = __fmaf_rn(wy1, r1r[xa0], __fmul_rn(wy0, r0r[xa0]));
    float ta1 = __fmaf_rn(wy1, r1r[xa1], __fmul_rn(wy0, r0r[xa1]));
    float va  = __fmaf_rn(wxa.y, ta1, __fmul_rn(wxa.x, ta0));
    float tb0 = __fmaf_rn(wy1, r1r[xb0], __fmul_rn(wy0, r0r[xb0]));
    float tb1 = __fmaf_rn(wy1, r1r[xb1], __fmul_rn(wy0, r0r[xb1]));
    float vb  = __fmaf_rn(wxb.y, tb1, __fmul_rn(wxb.x, tb0));
    float tc0 = __fmaf_rn(wy1, r1r[xc0], __fmul_rn(wy0, r0r[xc0]));
    float tc1 = __fmaf_rn(wy1, r1r[xc1], __fmul_rn(wy0, r0r[xc1]));
    float vc  = __fmaf_rn(wxc.y, tc1, __fmul_rn(wxc.x, tc0));
    float td0 = __fmaf_rn(wy1, r1r[xd0], __fmul_rn(wy0, r0r[xd0]));
    float td1 = __fmaf_rn(wy1, r1r[xd1], __fmul_rn(wy0, r0r[xd1]));
    float vd  = __fmaf_rn(wxd.y, td1, __fmul_rn(wxd.x, td0));
    vf4 res;
    res.x = (va > 0.0f) ? 1.0f : 0.0f;
    res.y = (vb > 0.0f) ? 1.0f : 0.0f;
    res.z = (vc > 0.0f) ? 1.0f : 0.0f;
    res.w = (vd > 0.0f) ? 1.0f : 0.0f;
    *(vf4*)optr = res;
  }
}

extern "C" void kernel_launch(void* const* d_in, const int* in_sizes, int n_in,
                              void* d_out, int out_size, void* d_ws, size_t ws_size,
                              hipStream_t stream) {
  const float* cls = (const float*)d_in[0];  // (300,81)
  const float* seg = (const float*)d_in[1];  // (300,200,200)
  float* out = (float*)d_out;
  char* ws = (char*)d_ws;

  u32* hist      = (u32*)(ws + WS_HIST);
  u64* keys      = (u64*)(ws + WS_KEYS);
  u64* collect   = (u64*)(ws + WS_COLLECT);
  u32* cnts      = (u32*)(ws + WS_CNT);
  float4* boxes  = (float4*)(ws + WS_BOXES);
  int* clab      = (int*)(ws + WS_CLAB);
  int* cfeat     = (int*)(ws + WS_CFEAT);
  float* cscore  = (float*)(ws + WS_CSCORE);
  float4* cbox   = (float4*)(ws + WS_CBOX);
  u64* rowT      = (u64*)(ws + WS_ROWBITS);
  int* selfeat   = (int*)(ws + WS_SELFEAT);

  r5_init<<<dim3(NBINS / 256), dim3(256), 0, stream>>>(hist, cnts);
  r5_boxes<<<dim3(NF), dim3(256), 0, stream>>>(seg, cls, boxes, keys, hist);
  r6_thresh<<<dim3(1), dim3(1024), 0, stream>>>(hist, cnts);
  r5_collect<<<dim3((NC + 255) / 256), dim3(256), 0, stream>>>(keys, cnts, collect, &cnts[0]);
  r5_rank<<<dim3(16), dim3(256), 0, stream>>>(collect, cnts, boxes, clab, cfeat, cscore, cbox);
  r7_iou<<<dim3(256), dim3(256), 0, stream>>>(cbox, rowT);
  r7_nms_sel<<<dim3(1), dim3(1024), 0, stream>>>(rowT, cscore, clab, cfeat, out, selfeat);
  r10_resize<<<dim3(1024 / RYC, MAXSEG), dim3(256), 0, stream>>>(seg, selfeat, out + OUT_MASK_OFF);
  r11_gather<<<dim3(1024, MAXSEG), dim3(256), 0, stream>>>(seg, selfeat, out + OUT_MASK_OFF);
}

// Round 13
// 655.481 us; speedup vs baseline: 2.1805x; 2.1805x over previous
//
#include <hip/hip_runtime.h>
#include <cstdint>
#include <cstddef>

typedef unsigned int u32;
typedef unsigned long long u64;
typedef float vf4 __attribute__((ext_vector_type(4)));

#define NF 300
#define NCLS 80
#define NCLS1 81
#define FH 200
#define FW 200
#define PIX 40000
#define NC 24000
#define KCAND 1000
#define CAP 4096
#define NBINS 65536
#define MAXSEG 100
#define OUT_MASK_OFF 100
#define OUT_SCORE_OFF 104857700
#define OUT_BATCH_OFF 104857800
#define NEG_BIG -3.3895313892515355e38f  /* finite sentinel, != -inf */

// workspace byte offsets
#define WS_HIST      0u        // 65536*4
#define WS_KEYS      262144u   // 24000*8
#define WS_COLLECT   454144u   // 4096*8
#define WS_CNT       486912u   // 4*4
#define WS_BOXES     486928u   // 300*16 (16B aligned)
#define WS_CLAB      496928u
#define WS_CFEAT     500928u
#define WS_CSCORE    504928u
#define WS_CBOX      508928u   // 1000*16 (16B aligned)
#define WS_ROWBITS   524928u   // 16*1024*8 TRANSPOSED: word ch, row i -> [ch*1024+i]
#define WS_SELFEAT   656128u   // 100*4

__device__ __forceinline__ u32 ord32_r3(float f) {
  u32 b = __float_as_uint(f);
  return (b & 0x80000000u) ? ~b : (b | 0x80000000u);
}
__device__ __forceinline__ float unord32_r3(u32 o) {
  u32 b = (o & 0x80000000u) ? (o & 0x7FFFFFFFu) : ~o;
  return __uint_as_float(b);
}

// Exact bilinear weight for output index i (1024 -> 200, same both axes).
__device__ __forceinline__ float4 wcalc_r4(int i) {
  float s = __fsub_rn(__fmul_rn((float)i + 0.5f, 0.1953125f), 0.5f);
  int j0 = (int)floorf(s);
  int j1 = j0 + 1;
  float w0 = fmaxf(0.f, __fsub_rn(1.f, fabsf(__fsub_rn(s, (float)j0))));
  float w1 = fmaxf(0.f, __fsub_rn(1.f, fabsf(__fsub_rn(s, (float)j1))));
  bool in0 = (j0 >= 0) && (j0 < FH);
  bool in1 = (j1 >= 0) && (j1 < FH);
  float tot = __fadd_rn(in0 ? w0 : 0.f, in1 ? w1 : 0.f);
  float w0n = in0 ? (w0 / tot) : 0.f;   // IEEE div
  float w1n = in1 ? (w1 / tot) : 0.f;
  return make_float4(w0n, w1n, (float)max(j0, 0), (float)min(j1, FH - 1));
}

// ---------------- A: zero hist + counters ----------------
__global__ void r5_init(u32* __restrict__ hist, u32* __restrict__ cnts) {
  int i = blockIdx.x * 256 + threadIdx.x;   // grid covers 65536
  hist[i] = 0u;
  if (i < 4) cnts[i] = 0u;
}

// ---------------- B: per-mask bbox + fused sigmoid scores/keys + global hist ------
__global__ void r5_boxes(const float* __restrict__ seg, const float* __restrict__ cls,
                         float4* __restrict__ boxes, u64* __restrict__ keys,
                         u32* __restrict__ hist) {
  __shared__ int sminx[256], sminy[256], smaxx[256], smaxy[256];
  int n = blockIdx.x, t = threadIdx.x;
  const float4* img = (const float4*)(seg + (size_t)n * PIX);
  int minx = FW, miny = FH, maxx = -1, maxy = -1;
  for (int q = t; q < PIX / 4; q += 256) {
    float4 v = img[q];
    int p = q * 4;
    int y = p / FW;
    int x = p - y * FW;
    if (v.x > 0.f) { minx = min(minx, x);     maxx = max(maxx, x);     miny = min(miny, y); maxy = max(maxy, y); }
    if (v.y > 0.f) { minx = min(minx, x + 1); maxx = max(maxx, x + 1); miny = min(miny, y); maxy = max(maxy, y); }
    if (v.z > 0.f) { minx = min(minx, x + 2); maxx = max(maxx, x + 2); miny = min(miny, y); maxy = max(maxy, y); }
    if (v.w > 0.f) { minx = min(minx, x + 3); maxx = max(maxx, x + 3); miny = min(miny, y); maxy = max(maxy, y); }
  }
  sminx[t] = minx; sminy[t] = miny; smaxx[t] = maxx; smaxy[t] = maxy;
  __syncthreads();
  for (int s = 128; s > 0; s >>= 1) {
    if (t < s) {
      sminx[t] = min(sminx[t], sminx[t + s]);
      sminy[t] = min(sminy[t], sminy[t + s]);
      smaxx[t] = max(smaxx[t], smaxx[t + s]);
      smaxy[t] = max(smaxy[t], smaxy[t + s]);
    }
    __syncthreads();
  }
  bool ne = smaxx[0] >= 0;
  if (t == 0) {
    float4 b;
    if (ne) b = make_float4((float)sminx[0], (float)sminy[0], (float)(smaxx[0] + 1), (float)(smaxy[0] + 1));
    else    b = make_float4(0.f, 0.f, (float)FW, (float)FH);  // argmax-of-all-false semantics
    boxes[n] = b;
  }
  if (t < NCLS) {
    float sc;
    if (ne) {
      float lg = cls[n * NCLS1 + t];
      sc = 1.0f / (1.0f + expf(-lg));
    } else {
      sc = -1.0f;
    }
    u32 o = ord32_r3(sc);
    u32 i = (u32)(n * NCLS + t);
    keys[i] = ((u64)o << 32) | (u64)(0xFFFFFFFFu - i);  // lower index -> larger key on ties
    atomicAdd(&hist[o >> 16], 1u);
  }
}

// ---------------- C: histogram bin of the 1000th largest key (uint4 loads) --------
__global__ void r6_thresh(const u32* __restrict__ hist, u32* __restrict__ cnts) {
  __shared__ u32 s[1024];
  int t = threadIdx.x;
  const uint4* hp = (const uint4*)(hist) + t * 16;
  u32 sum = 0;
  #pragma unroll
  for (int b = 0; b < 16; b++) {
    uint4 v = hp[b];
    sum += v.x + v.y + v.z + v.w;
  }
  s[t] = sum;
  __syncthreads();
  for (int off = 1; off < 1024; off <<= 1) {
    u32 v = s[t];
    u32 o = (t + off < 1024) ? s[t + off] : 0u;
    __syncthreads();
    s[t] = v + o;
    __syncthreads();
  }
  u32 sufnext = (t < 1023) ? s[t + 1] : 0u;
  if (s[t] >= (u32)KCAND && sufnext < (u32)KCAND) {
    u32 run = sufnext;
    u32 B = (u32)(t * 64);
    for (int b = 63; b >= 0; b--) {
      run += hist[t * 64 + b];
      if (run >= (u32)KCAND) { B = (u32)(t * 64 + b); break; }
    }
    cnts[1] = B;
  }
}

// ---------------- D: collect (wave-aggregated atomic) ----------------
__global__ void r5_collect(const u64* __restrict__ keys, const u32* __restrict__ cnts,
                           u64* __restrict__ collect, u32* __restrict__ counter) {
  int i = blockIdx.x * 256 + threadIdx.x;
  u32 B = cnts[1];
  bool pass = false;
  u64 k = 0ull;
  if (i < NC) {
    k = keys[i];
    pass = ((u32)(k >> 48) >= B);
  }
  u64 m = __ballot(pass);
  int lane = threadIdx.x & 63;
  u32 base = 0u;
  if (lane == 0 && m) base = atomicAdd(counter, (u32)__popcll(m));
  base = __shfl(base, 0, 64);
  if (pass) {
    u32 pos = base + (u32)__popcll(m & ((1ull << lane) - 1ull));
    if (pos < CAP) collect[pos] = k;
  }
}

// ---------------- E: exact stable rank, 16 blocks x 256 --------
__global__ void r5_rank(const u64* __restrict__ collect, const u32* __restrict__ cnts,
                        const float4* __restrict__ boxes,
                        int* __restrict__ clab, int* __restrict__ cfeat,
                        float* __restrict__ cscore, float4* __restrict__ cbox) {
  __shared__ u64 sk[CAP];
  int M = min((int)cnts[0], CAP);
  int t = threadIdx.x;
  for (int j = t; j < M; j += 256) sk[j] = collect[j];
  __syncthreads();
  int j = blockIdx.x * 256 + t;   // 16*256 = 4096 = CAP covers all M
  if (j < M) {
    u64 my = sk[j];
    int r = 0;
    for (int k = 0; k < M; k++) r += (sk[k] > my) ? 1 : 0;
    if (r < KCAND) {
      u32 idx = 0xFFFFFFFFu - (u32)(my & 0xFFFFFFFFull);
      int n = (int)idx / NCLS, c = (int)idx - n * NCLS;
      clab[r] = c;
      cfeat[r] = n;
      cscore[r] = unord32_r3((u32)(my >> 32));
      float4 b = boxes[n];
      float off = (float)c * 201.0f;  // label * (max(fH,fW)+1) on all 4 coords
      cbox[r] = make_float4(b.x + off, b.y + off, b.z + off, b.w + off);
    }
  }
}

// ---------------- F: IoU > thr bitmask rows, TRANSPOSED [word][row] layout --------
__global__ void r7_iou(const float4* __restrict__ cbox, u64* __restrict__ rowT) {
  __shared__ float4 sb[KCAND];
  int t = threadIdx.x;
  for (int j = t; j < KCAND; j += 256) sb[j] = cbox[j];
  __syncthreads();
  int w = t >> 6, lane = t & 63;
  int i = blockIdx.x * 4 + w;     // 256 blocks -> rows 0..1023 (rows >=1000 write 0)
  float4 bi = make_float4(0.f, 0.f, 0.f, 0.f);
  float ai = 0.f;
  if (i < KCAND) { bi = sb[i]; ai = (bi.z - bi.x) * (bi.w - bi.y); }
  for (int ch = 0; ch < 16; ch++) {
    int j = ch * 64 + lane;
    bool pred = false;
    if (i < KCAND && j < KCAND && j > i) {
      float4 bj = sb[j];
      float aj = (bj.z - bj.x) * (bj.w - bj.y);
      float ix1 = fmaxf(bi.x, bj.x), iy1 = fmaxf(bi.y, bj.y);
      float ix2 = fminf(bi.z, bj.z), iy2 = fminf(bi.w, bj.w);
      float inter = fmaxf(ix2 - ix1, 0.f) * fmaxf(iy2 - iy1, 0.f);
      float uni = ai + aj - inter;
      float iou = inter / fmaxf(uni, 1e-9f);
      pred = iou > 0.65f;
    }
    u64 m = __ballot(pred);
    if (lane == 0) rowT[(size_t)ch * 1024 + i] = m;
  }
}

// ---------------- G: greedy NMS scan, wave-parallel propagation + selection -------
__global__ void r7_nms_sel(const u64* __restrict__ rowT, const float* __restrict__ cscore,
                           const int* __restrict__ clab, const int* __restrict__ cfeat,
                           float* __restrict__ out, int* __restrict__ selfeat) {
  __shared__ u64 sup[16];
  __shared__ u64 keep[16];
  __shared__ u64 sel[16];
  __shared__ u32 pre[17];
  int t = threadIdx.x;
  int wv = t >> 6, lane = t & 63;
  if (t < 16) sup[t] = 0ull;
  __syncthreads();
  for (int c = 0; c < 16; c++) {
    u64 row = 0ull;
    if (wv > c) row = rowT[(size_t)wv * 1024 + c * 64 + lane];
    if (wv == 0) {
      u64 r = rowT[(size_t)c * 1024 + c * 64 + lane];  // diag word, coalesced
      u64 s = sup[c];
      u64 k = 0ull;
      #pragma unroll
      for (int b = 0; b < 64; b++) {
        u64 rb = __shfl(r, b, 64);   // constant b -> v_readlane
        if (!((s >> b) & 1ull)) { s |= rb; k |= (1ull << b); }
      }
      if (lane == 0) keep[c] = k;
    }
    __syncthreads();
    if (wv > c) {
      u64 kk = keep[c];
      u64 acc = ((kk >> lane) & 1ull) ? row : 0ull;
      #pragma unroll
      for (int off = 32; off >= 1; off >>= 1) acc |= __shfl_xor(acc, off, 64);
      if (lane == 0) sup[wv] |= acc;
    }
    __syncthreads();
  }
  {
    bool s = false;
    if (t < KCAND) {
      bool kp = ((keep[t >> 6] >> (t & 63)) & 1ull) != 0ull;
      s = kp && (cscore[t] >= 0.f);
    }
    u64 m = __ballot(s);
    if (lane == 0) sel[wv] = m;
  }
  __syncthreads();
  if (t == 0) {
    u32 acc = 0;
    #pragma unroll
    for (int c = 0; c < 16; c++) { pre[c] = acc; acc += (u32)__popcll(sel[c]); }
    pre[16] = acc;
  }
  __syncthreads();
  u32 nkept = pre[16];
  if (t < KCAND) {
    int j = t;
    u64 w = sel[j >> 6];
    bool s = ((w >> (j & 63)) & 1ull) != 0ull;
    u32 below = pre[j >> 6] + (u32)__popcll(w & ((1ull << (j & 63)) - 1ull));
    u32 r = s ? below : (nkept + (u32)j - below);
    if (r < MAXSEG) {
      out[r] = (float)clab[j];
      out[OUT_SCORE_OFF + r] = s ? cscore[j] : NEG_BIG;
      out[OUT_BATCH_OFF + r] = 0.0f;
      selfeat[r] = cfeat[j];
    }
  }
}

// ---------------- R: gather resize with DEDUPED loads (bit-identical math) --------
// Round-12 A/B findings: gather (no LDS/barriers) runs at 75% occupancy and is
// L2-load-bound: 16 scalar loads/thread = 1.68 GB of L2 requests, but a thread's
// 4 outputs span <1 input pixel (4*0.1953=0.78) -> taps cover <=3 columns x 2
// rows = 6 distinct values. Load those 6, H-contract 3 columns once, select taps
// branchlessly. Same fma/mul sequence on same values -> bit-identical outputs.
// Stores issue from cycle ~0 in every block -> best overlap with the 419 MB
// HBM write drain (the structural floor, ~66us at fill-rate).
__global__ void __launch_bounds__(256) r12_resize(const float* __restrict__ seg,
                                                  const int* __restrict__ selfeat,
                                                  float* __restrict__ outm) {
  int t = threadIdx.x;
  int row = blockIdx.x;          // output row 0..1023
  int slot = blockIdx.y;
  int feat = selfeat[slot];
  const float* img = seg + (size_t)feat * PIX;
  float4 wy = wcalc_r4(row);
  const float* r0 = img + (int)wy.z * FW;
  const float* r1 = img + (int)wy.w * FW;
  float wy0 = wy.x, wy1 = wy.y;
  float4 wxa = wcalc_r4(t * 4), wxb = wcalc_r4(t * 4 + 1),
         wxc = wcalc_r4(t * 4 + 2), wxd = wcalc_r4(t * 4 + 3);
  int c0 = (int)wxa.z;                      // leftmost tap of this thread
  int c1 = min(c0 + 1, FW - 1);
  int c2 = min(c0 + 2, FW - 1);
  // 6 deduped loads (L2-hot)
  float a0 = r0[c0], a1 = r0[c1], a2 = r0[c2];
  float b0 = r1[c0], b1 = r1[c1], b2 = r1[c2];
  // H contraction per distinct column — identical op order to previous kernels
  float h0 = __fmaf_rn(wy1, b0, __fmul_rn(wy0, a0));
  float h1 = __fmaf_rn(wy1, b1, __fmul_rn(wy0, a1));
  float h2 = __fmaf_rn(wy1, b2, __fmul_rn(wy0, a2));
  // branchless tap select by (index - c0) in {0,1,2}
  #define PICK(x) ((x) == c0 ? h0 : ((x) == c0 + 1 ? h1 : h2))
  float va = __fmaf_rn(wxa.y, PICK((int)wxa.w), __fmul_rn(wxa.x, h0));
  float vb = __fmaf_rn(wxb.y, PICK((int)wxb.w), __fmul_rn(wxb.x, PICK((int)wxb.z)));
  float vc = __fmaf_rn(wxc.y, PICK((int)wxc.w), __fmul_rn(wxc.x, PICK((int)wxc.z)));
  float vd = __fmaf_rn(wxd.y, PICK((int)wxd.w), __fmul_rn(wxd.x, PICK((int)wxd.z)));
  #undef PICK
  vf4 res;
  res.x = (va > 0.0f) ? 1.0f : 0.0f;
  res.y = (vb > 0.0f) ? 1.0f : 0.0f;
  res.z = (vc > 0.0f) ? 1.0f : 0.0f;
  res.w = (vd > 0.0f) ? 1.0f : 0.0f;
  *(vf4*)(outm + (size_t)slot * 1048576 + (size_t)row * 1024 + t * 4) = res;
}

extern "C" void kernel_launch(void* const* d_in, const int* in_sizes, int n_in,
                              void* d_out, int out_size, void* d_ws, size_t ws_size,
                              hipStream_t stream) {
  const float* cls = (const float*)d_in[0];  // (300,81)
  const float* seg = (const float*)d_in[1];  // (300,200,200)
  float* out = (float*)d_out;
  char* ws = (char*)d_ws;

  u32* hist      = (u32*)(ws + WS_HIST);
  u64* keys      = (u64*)(ws + WS_KEYS);
  u64* collect   = (u64*)(ws + WS_COLLECT);
  u32* cnts      = (u32*)(ws + WS_CNT);
  float4* boxes  = (float4*)(ws + WS_BOXES);
  int* clab      = (int*)(ws + WS_CLAB);
  int* cfeat     = (int*)(ws + WS_CFEAT);
  float* cscore  = (float*)(ws + WS_CSCORE);
  float4* cbox   = (float4*)(ws + WS_CBOX);
  u64* rowT      = (u64*)(ws + WS_ROWBITS);
  int* selfeat   = (int*)(ws + WS_SELFEAT);

  r5_init<<<dim3(NBINS / 256), dim3(256), 0, stream>>>(hist, cnts);
  r5_boxes<<<dim3(NF), dim3(256), 0, stream>>>(seg, cls, boxes, keys, hist);
  r6_thresh<<<dim3(1), dim3(1024), 0, stream>>>(hist, cnts);
  r5_collect<<<dim3((NC + 255) / 256), dim3(256), 0, stream>>>(keys, cnts, collect, &cnts[0]);
  r5_rank<<<dim3(16), dim3(256), 0, stream>>>(collect, cnts, boxes, clab, cfeat, cscore, cbox);
  r7_iou<<<dim3(256), dim3(256), 0, stream>>>(cbox, rowT);
  r7_nms_sel<<<dim3(1), dim3(1024), 0, stream>>>(rowT, cscore, clab, cfeat, out, selfeat);
  r12_resize<<<dim3(1024, MAXSEG), dim3(256), 0, stream>>>(seg, selfeat, out + OUT_MASK_OFF);
}

// Round 14
// 628.802 us; speedup vs baseline: 2.2730x; 1.0424x over previous
//
#include <hip/hip_runtime.h>
#include <cstdint>
#include <cstddef>

typedef unsigned int u32;
typedef unsigned long long u64;
typedef float vf4 __attribute__((ext_vector_type(4)));

#define NF 300
#define NCLS 80
#define NCLS1 81
#define FH 200
#define FW 200
#define PIX 40000
#define NC 24000
#define KCAND 1000
#define CAP 4096
#define NBINS 65536
#define MAXSEG 100
#define OUT_MASK_OFF 100
#define OUT_SCORE_OFF 104857700
#define OUT_BATCH_OFF 104857800
#define NEG_BIG -3.3895313892515355e38f  /* finite sentinel, != -inf */

// workspace byte offsets
#define WS_HIST      0u        // 65536*4
#define WS_KEYS      262144u   // 24000*8
#define WS_COLLECT   454144u   // 4096*8
#define WS_CNT       486912u   // 4*4
#define WS_BOXES     486928u   // 300*16 (16B aligned)
#define WS_CLAB      496928u
#define WS_CFEAT     500928u
#define WS_CSCORE    504928u
#define WS_CBOX      508928u   // 1000*16 (16B aligned)
#define WS_ROWBITS   524928u   // 16*1024*8 TRANSPOSED: word ch, row i -> [ch*1024+i]
#define WS_SELFEAT   656128u   // 100*4
#define WS_WTAB      656528u   // 1024*16 (16B aligned) resize weight table

__device__ __forceinline__ u32 ord32_r3(float f) {
  u32 b = __float_as_uint(f);
  return (b & 0x80000000u) ? ~b : (b | 0x80000000u);
}
__device__ __forceinline__ float unord32_r3(u32 o) {
  u32 b = (o & 0x80000000u) ? (o & 0x7FFFFFFFu) : ~o;
  return __uint_as_float(b);
}

// ---------------- A: zero hist/cnts + build resize weight table ----------------
// wtab[i] identical arithmetic to the inline wcalc of previous rounds. Round-13
// lesson: at 102400 gather blocks, inline weight calc = 131M calls x ~100cyc
// (2 IEEE divs each) ~ 160us of VALU tax; the table costs ~4us once.
__global__ void r13_init(u32* __restrict__ hist, u32* __restrict__ cnts,
                         float4* __restrict__ wtab) {
  int i = blockIdx.x * 256 + threadIdx.x;   // grid covers 65536
  hist[i] = 0u;
  if (i < 4) cnts[i] = 0u;
  if (i < 1024) {
    float s = __fsub_rn(__fmul_rn((float)i + 0.5f, 0.1953125f), 0.5f);
    int j0 = (int)floorf(s);
    int j1 = j0 + 1;
    float w0 = fmaxf(0.f, __fsub_rn(1.f, fabsf(__fsub_rn(s, (float)j0))));
    float w1 = fmaxf(0.f, __fsub_rn(1.f, fabsf(__fsub_rn(s, (float)j1))));
    bool in0 = (j0 >= 0) && (j0 < FH);
    bool in1 = (j1 >= 0) && (j1 < FH);
    float tot = __fadd_rn(in0 ? w0 : 0.f, in1 ? w1 : 0.f);
    float w0n = in0 ? (w0 / tot) : 0.f;   // IEEE div
    float w1n = in1 ? (w1 / tot) : 0.f;
    wtab[i] = make_float4(w0n, w1n, (float)max(j0, 0), (float)min(j1, FH - 1));
  }
}

// ---------------- B: per-mask bbox + fused sigmoid scores/keys + global hist ------
__global__ void r5_boxes(const float* __restrict__ seg, const float* __restrict__ cls,
                         float4* __restrict__ boxes, u64* __restrict__ keys,
                         u32* __restrict__ hist) {
  __shared__ int sminx[256], sminy[256], smaxx[256], smaxy[256];
  int n = blockIdx.x, t = threadIdx.x;
  const float4* img = (const float4*)(seg + (size_t)n * PIX);
  int minx = FW, miny = FH, maxx = -1, maxy = -1;
  for (int q = t; q < PIX / 4; q += 256) {
    float4 v = img[q];
    int p = q * 4;
    int y = p / FW;
    int x = p - y * FW;
    if (v.x > 0.f) { minx = min(minx, x);     maxx = max(maxx, x);     miny = min(miny, y); maxy = max(maxy, y); }
    if (v.y > 0.f) { minx = min(minx, x + 1); maxx = max(maxx, x + 1); miny = min(miny, y); maxy = max(maxy, y); }
    if (v.z > 0.f) { minx = min(minx, x + 2); maxx = max(maxx, x + 2); miny = min(miny, y); maxy = max(maxy, y); }
    if (v.w > 0.f) { minx = min(minx, x + 3); maxx = max(maxx, x + 3); miny = min(miny, y); maxy = max(maxy, y); }
  }
  sminx[t] = minx; sminy[t] = miny; smaxx[t] = maxx; smaxy[t] = maxy;
  __syncthreads();
  for (int s = 128; s > 0; s >>= 1) {
    if (t < s) {
      sminx[t] = min(sminx[t], sminx[t + s]);
      sminy[t] = min(sminy[t], sminy[t + s]);
      smaxx[t] = max(smaxx[t], smaxx[t + s]);
      smaxy[t] = max(smaxy[t], smaxy[t + s]);
    }
    __syncthreads();
  }
  bool ne = smaxx[0] >= 0;
  if (t == 0) {
    float4 b;
    if (ne) b = make_float4((float)sminx[0], (float)sminy[0], (float)(smaxx[0] + 1), (float)(smaxy[0] + 1));
    else    b = make_float4(0.f, 0.f, (float)FW, (float)FH);  // argmax-of-all-false semantics
    boxes[n] = b;
  }
  if (t < NCLS) {
    float sc;
    if (ne) {
      float lg = cls[n * NCLS1 + t];
      sc = 1.0f / (1.0f + expf(-lg));
    } else {
      sc = -1.0f;
    }
    u32 o = ord32_r3(sc);
    u32 i = (u32)(n * NCLS + t);
    keys[i] = ((u64)o << 32) | (u64)(0xFFFFFFFFu - i);  // lower index -> larger key on ties
    atomicAdd(&hist[o >> 16], 1u);
  }
}

// ---------------- C: histogram bin of the 1000th largest key (uint4 loads) --------
__global__ void r6_thresh(const u32* __restrict__ hist, u32* __restrict__ cnts) {
  __shared__ u32 s[1024];
  int t = threadIdx.x;
  const uint4* hp = (const uint4*)(hist) + t * 16;
  u32 sum = 0;
  #pragma unroll
  for (int b = 0; b < 16; b++) {
    uint4 v = hp[b];
    sum += v.x + v.y + v.z + v.w;
  }
  s[t] = sum;
  __syncthreads();
  for (int off = 1; off < 1024; off <<= 1) {
    u32 v = s[t];
    u32 o = (t + off < 1024) ? s[t + off] : 0u;
    __syncthreads();
    s[t] = v + o;
    __syncthreads();
  }
  u32 sufnext = (t < 1023) ? s[t + 1] : 0u;
  if (s[t] >= (u32)KCAND && sufnext < (u32)KCAND) {
    u32 run = sufnext;
    u32 B = (u32)(t * 64);
    for (int b = 63; b >= 0; b--) {
      run += hist[t * 64 + b];
      if (run >= (u32)KCAND) { B = (u32)(t * 64 + b); break; }
    }
    cnts[1] = B;
  }
}

// ---------------- D: collect (wave-aggregated atomic) ----------------
__global__ void r5_collect(const u64* __restrict__ keys, const u32* __restrict__ cnts,
                           u64* __restrict__ collect, u32* __restrict__ counter) {
  int i = blockIdx.x * 256 + threadIdx.x;
  u32 B = cnts[1];
  bool pass = false;
  u64 k = 0ull;
  if (i < NC) {
    k = keys[i];
    pass = ((u32)(k >> 48) >= B);
  }
  u64 m = __ballot(pass);
  int lane = threadIdx.x & 63;
  u32 base = 0u;
  if (lane == 0 && m) base = atomicAdd(counter, (u32)__popcll(m));
  base = __shfl(base, 0, 64);
  if (pass) {
    u32 pos = base + (u32)__popcll(m & ((1ull << lane) - 1ull));
    if (pos < CAP) collect[pos] = k;
  }
}

// ---------------- E: exact stable rank, 16 blocks x 256 --------
__global__ void r5_rank(const u64* __restrict__ collect, const u32* __restrict__ cnts,
                        const float4* __restrict__ boxes,
                        int* __restrict__ clab, int* __restrict__ cfeat,
                        float* __restrict__ cscore, float4* __restrict__ cbox) {
  __shared__ u64 sk[CAP];
  int M = min((int)cnts[0], CAP);
  int t = threadIdx.x;
  for (int j = t; j < M; j += 256) sk[j] = collect[j];
  __syncthreads();
  int j = blockIdx.x * 256 + t;   // 16*256 = 4096 = CAP covers all M
  if (j < M) {
    u64 my = sk[j];
    int r = 0;
    for (int k = 0; k < M; k++) r += (sk[k] > my) ? 1 : 0;
    if (r < KCAND) {
      u32 idx = 0xFFFFFFFFu - (u32)(my & 0xFFFFFFFFull);
      int n = (int)idx / NCLS, c = (int)idx - n * NCLS;
      clab[r] = c;
      cfeat[r] = n;
      cscore[r] = unord32_r3((u32)(my >> 32));
      float4 b = boxes[n];
      float off = (float)c * 201.0f;  // label * (max(fH,fW)+1) on all 4 coords
      cbox[r] = make_float4(b.x + off, b.y + off, b.z + off, b.w + off);
    }
  }
}

// ---------------- F: IoU > thr bitmask rows, TRANSPOSED [word][row] layout --------
__global__ void r7_iou(const float4* __restrict__ cbox, u64* __restrict__ rowT) {
  __shared__ float4 sb[KCAND];
  int t = threadIdx.x;
  for (int j = t; j < KCAND; j += 256) sb[j] = cbox[j];
  __syncthreads();
  int w = t >> 6, lane = t & 63;
  int i = blockIdx.x * 4 + w;     // 256 blocks -> rows 0..1023 (rows >=1000 write 0)
  float4 bi = make_float4(0.f, 0.f, 0.f, 0.f);
  float ai = 0.f;
  if (i < KCAND) { bi = sb[i]; ai = (bi.z - bi.x) * (bi.w - bi.y); }
  for (int ch = 0; ch < 16; ch++) {
    int j = ch * 64 + lane;
    bool pred = false;
    if (i < KCAND && j < KCAND && j > i) {
      float4 bj = sb[j];
      float aj = (bj.z - bj.x) * (bj.w - bj.y);
      float ix1 = fmaxf(bi.x, bj.x), iy1 = fmaxf(bi.y, bj.y);
      float ix2 = fminf(bi.z, bj.z), iy2 = fminf(bi.w, bj.w);
      float inter = fmaxf(ix2 - ix1, 0.f) * fmaxf(iy2 - iy1, 0.f);
      float uni = ai + aj - inter;
      float iou = inter / fmaxf(uni, 1e-9f);
      pred = iou > 0.65f;
    }
    u64 m = __ballot(pred);
    if (lane == 0) rowT[(size_t)ch * 1024 + i] = m;
  }
}

// ---------------- G: greedy NMS scan, wave-parallel propagation + selection -------
__global__ void r7_nms_sel(const u64* __restrict__ rowT, const float* __restrict__ cscore,
                           const int* __restrict__ clab, const int* __restrict__ cfeat,
                           float* __restrict__ out, int* __restrict__ selfeat) {
  __shared__ u64 sup[16];
  __shared__ u64 keep[16];
  __shared__ u64 sel[16];
  __shared__ u32 pre[17];
  int t = threadIdx.x;
  int wv = t >> 6, lane = t & 63;
  if (t < 16) sup[t] = 0ull;
  __syncthreads();
  for (int c = 0; c < 16; c++) {
    u64 row = 0ull;
    if (wv > c) row = rowT[(size_t)wv * 1024 + c * 64 + lane];
    if (wv == 0) {
      u64 r = rowT[(size_t)c * 1024 + c * 64 + lane];  // diag word, coalesced
      u64 s = sup[c];
      u64 k = 0ull;
      #pragma unroll
      for (int b = 0; b < 64; b++) {
        u64 rb = __shfl(r, b, 64);   // constant b -> v_readlane
        if (!((s >> b) & 1ull)) { s |= rb; k |= (1ull << b); }
      }
      if (lane == 0) keep[c] = k;
    }
    __syncthreads();
    if (wv > c) {
      u64 kk = keep[c];
      u64 acc = ((kk >> lane) & 1ull) ? row : 0ull;
      #pragma unroll
      for (int off = 32; off >= 1; off >>= 1) acc |= __shfl_xor(acc, off, 64);
      if (lane == 0) sup[wv] |= acc;
    }
    __syncthreads();
  }
  {
    bool s = false;
    if (t < KCAND) {
      bool kp = ((keep[t >> 6] >> (t & 63)) & 1ull) != 0ull;
      s = kp && (cscore[t] >= 0.f);
    }
    u64 m = __ballot(s);
    if (lane == 0) sel[wv] = m;
  }
  __syncthreads();
  if (t == 0) {
    u32 acc = 0;
    #pragma unroll
    for (int c = 0; c < 16; c++) { pre[c] = acc; acc += (u32)__popcll(sel[c]); }
    pre[16] = acc;
  }
  __syncthreads();
  u32 nkept = pre[16];
  if (t < KCAND) {
    int j = t;
    u64 w = sel[j >> 6];
    bool s = ((w >> (j & 63)) & 1ull) != 0ull;
    u32 below = pre[j >> 6] + (u32)__popcll(w & ((1ull << (j & 63)) - 1ull));
    u32 r = s ? below : (nkept + (u32)j - below);
    if (r < MAXSEG) {
      out[r] = (float)clab[j];
      out[OUT_SCORE_OFF + r] = s ? cscore[j] : NEG_BIG;
      out[OUT_BATCH_OFF + r] = 0.0f;
      selfeat[r] = cfeat[j];
    }
  }
}

// ---------------- R: gather resize, deduped loads + WEIGHT TABLE ----------------
// Structure proven by the r11/r12 A/B: no LDS, no barriers, 1 row/block, stores
// issue immediately -> best overlap with the 419 MB write drain. Weights come
// from wtab (L2-hot): 1 uniform row entry + 4 coalesced float4 per thread.
// Math identical to all previous resize variants -> bit-identical output.
__global__ void __launch_bounds__(256) r13_resize(const float* __restrict__ seg,
                                                  const int* __restrict__ selfeat,
                                                  const float4* __restrict__ wtab,
                                                  float* __restrict__ outm) {
  int t = threadIdx.x;
  int row = blockIdx.x;          // output row 0..1023
  int slot = blockIdx.y;
  int feat = selfeat[slot];
  const float* img = seg + (size_t)feat * PIX;
  float4 wy = wtab[row];         // uniform across block -> scalar load
  const float* r0 = img + (int)wy.z * FW;
  const float* r1 = img + (int)wy.w * FW;
  float wy0 = wy.x, wy1 = wy.y;
  float4 wxa = wtab[t * 4], wxb = wtab[t * 4 + 1],
         wxc = wtab[t * 4 + 2], wxd = wtab[t * 4 + 3];
  int c0 = (int)wxa.z;                      // leftmost tap of this thread
  int c1 = min(c0 + 1, FW - 1);
  int c2 = min(c0 + 2, FW - 1);
  // 6 deduped loads (L2-hot; a thread's 4 outputs span <=3 cols x 2 rows)
  float a0 = r0[c0], a1 = r0[c1], a2 = r0[c2];
  float b0 = r1[c0], b1 = r1[c1], b2 = r1[c2];
  // H contraction per distinct column — identical op order to previous kernels
  float h0 = __fmaf_rn(wy1, b0, __fmul_rn(wy0, a0));
  float h1 = __fmaf_rn(wy1, b1, __fmul_rn(wy0, a1));
  float h2 = __fmaf_rn(wy1, b2, __fmul_rn(wy0, a2));
  // branchless tap select by (index - c0) in {0,1,2}
  #define PICK(x) ((x) == c0 ? h0 : ((x) == c0 + 1 ? h1 : h2))
  float va = __fmaf_rn(wxa.y, PICK((int)wxa.w), __fmul_rn(wxa.x, h0));
  float vb = __fmaf_rn(wxb.y, PICK((int)wxb.w), __fmul_rn(wxb.x, PICK((int)wxb.z)));
  float vc = __fmaf_rn(wxc.y, PICK((int)wxc.w), __fmul_rn(wxc.x, PICK((int)wxc.z)));
  float vd = __fmaf_rn(wxd.y, PICK((int)wxd.w), __fmul_rn(wxd.x, PICK((int)wxd.z)));
  #undef PICK
  vf4 res;
  res.x = (va > 0.0f) ? 1.0f : 0.0f;
  res.y = (vb > 0.0f) ? 1.0f : 0.0f;
  res.z = (vc > 0.0f) ? 1.0f : 0.0f;
  res.w = (vd > 0.0f) ? 1.0f : 0.0f;
  *(vf4*)(outm + (size_t)slot * 1048576 + (size_t)row * 1024 + t * 4) = res;
}

extern "C" void kernel_launch(void* const* d_in, const int* in_sizes, int n_in,
                              void* d_out, int out_size, void* d_ws, size_t ws_size,
                              hipStream_t stream) {
  const float* cls = (const float*)d_in[0];  // (300,81)
  const float* seg = (const float*)d_in[1];  // (300,200,200)
  float* out = (float*)d_out;
  char* ws = (char*)d_ws;

  u32* hist      = (u32*)(ws + WS_HIST);
  u64* keys      = (u64*)(ws + WS_KEYS);
  u64* collect   = (u64*)(ws + WS_COLLECT);
  u32* cnts      = (u32*)(ws + WS_CNT);
  float4* boxes  = (float4*)(ws + WS_BOXES);
  int* clab      = (int*)(ws + WS_CLAB);
  int* cfeat     = (int*)(ws + WS_CFEAT);
  float* cscore  = (float*)(ws + WS_CSCORE);
  float4* cbox   = (float4*)(ws + WS_CBOX);
  u64* rowT      = (u64*)(ws + WS_ROWBITS);
  int* selfeat   = (int*)(ws + WS_SELFEAT);
  float4* wtab   = (float4*)(ws + WS_WTAB);

  r13_init<<<dim3(NBINS / 256), dim3(256), 0, stream>>>(hist, cnts, wtab);
  r5_boxes<<<dim3(NF), dim3(256), 0, stream>>>(seg, cls, boxes, keys, hist);
  r6_thresh<<<dim3(1), dim3(1024), 0, stream>>>(hist, cnts);
  r5_collect<<<dim3((NC + 255) / 256), dim3(256), 0, stream>>>(keys, cnts, collect, &cnts[0]);
  r5_rank<<<dim3(16), dim3(256), 0, stream>>>(collect, cnts, boxes, clab, cfeat, cscore, cbox);
  r7_iou<<<dim3(256), dim3(256), 0, stream>>>(cbox, rowT);
  r7_nms_sel<<<dim3(1), dim3(1024), 0, stream>>>(rowT, cscore, clab, cfeat, out, selfeat);
  r13_resize<<<dim3(1024, MAXSEG), dim3(256), 0, stream>>>(seg, selfeat, wtab, out + OUT_MASK_OFF);
}

// Round 15
// 571.760 us; speedup vs baseline: 2.4998x; 1.0998x over previous
//
#include <hip/hip_runtime.h>
#include <cstdint>
#include <cstddef>

typedef unsigned int u32;
typedef unsigned long long u64;
typedef float vf4 __attribute__((ext_vector_type(4)));

#define NF 300
#define NCLS 80
#define NCLS1 81
#define FH 200
#define FW 200
#define PIX 40000
#define NC 24000
#define KCAND 1000
#define CAP 4096
#define NBINS 65536
#define MAXSEG 100
#define OUT_MASK_OFF 100
#define OUT_SCORE_OFF 104857700
#define OUT_BATCH_OFF 104857800
#define NEG_BIG -3.3895313892515355e38f  /* finite sentinel, != -inf */
#define RPB 8   /* output rows per resize block (multi-row gather) */

// workspace byte offsets
#define WS_HIST      0u        // 65536*4
#define WS_KEYS      262144u   // 24000*8
#define WS_COLLECT   454144u   // 4096*8
#define WS_CNT       486912u   // 4*4
#define WS_BOXES     486928u   // 300*16 (16B aligned)
#define WS_CLAB      496928u
#define WS_CFEAT     500928u
#define WS_CSCORE    504928u
#define WS_CBOX      508928u   // 1000*16 (16B aligned)
#define WS_ROWBITS   524928u   // 16*1024*8 TRANSPOSED: word ch, row i -> [ch*1024+i]
#define WS_SELFEAT   656128u   // 100*4
#define WS_WTAB      656528u   // 1024*16 (16B aligned) resize weight table

__device__ __forceinline__ u32 ord32_r3(float f) {
  u32 b = __float_as_uint(f);
  return (b & 0x80000000u) ? ~b : (b | 0x80000000u);
}
__device__ __forceinline__ float unord32_r3(u32 o) {
  u32 b = (o & 0x80000000u) ? (o & 0x7FFFFFFFu) : ~o;
  return __uint_as_float(b);
}

// ---------------- A: zero hist/cnts + build resize weight table ----------------
// wtab[i] identical arithmetic to the inline wcalc of previous rounds.
__global__ void r13_init(u32* __restrict__ hist, u32* __restrict__ cnts,
                         float4* __restrict__ wtab) {
  int i = blockIdx.x * 256 + threadIdx.x;   // grid covers 65536
  hist[i] = 0u;
  if (i < 4) cnts[i] = 0u;
  if (i < 1024) {
    float s = __fsub_rn(__fmul_rn((float)i + 0.5f, 0.1953125f), 0.5f);
    int j0 = (int)floorf(s);
    int j1 = j0 + 1;
    float w0 = fmaxf(0.f, __fsub_rn(1.f, fabsf(__fsub_rn(s, (float)j0))));
    float w1 = fmaxf(0.f, __fsub_rn(1.f, fabsf(__fsub_rn(s, (float)j1))));
    bool in0 = (j0 >= 0) && (j0 < FH);
    bool in1 = (j1 >= 0) && (j1 < FH);
    float tot = __fadd_rn(in0 ? w0 : 0.f, in1 ? w1 : 0.f);
    float w0n = in0 ? (w0 / tot) : 0.f;   // IEEE div
    float w1n = in1 ? (w1 / tot) : 0.f;
    wtab[i] = make_float4(w0n, w1n, (float)max(j0, 0), (float)min(j1, FH - 1));
  }
}

// ---------------- B: per-mask bbox + fused sigmoid scores/keys + global hist ------
__global__ void r5_boxes(const float* __restrict__ seg, const float* __restrict__ cls,
                         float4* __restrict__ boxes, u64* __restrict__ keys,
                         u32* __restrict__ hist) {
  __shared__ int sminx[256], sminy[256], smaxx[256], smaxy[256];
  int n = blockIdx.x, t = threadIdx.x;
  const float4* img = (const float4*)(seg + (size_t)n * PIX);
  int minx = FW, miny = FH, maxx = -1, maxy = -1;
  for (int q = t; q < PIX / 4; q += 256) {
    float4 v = img[q];
    int p = q * 4;
    int y = p / FW;
    int x = p - y * FW;
    if (v.x > 0.f) { minx = min(minx, x);     maxx = max(maxx, x);     miny = min(miny, y); maxy = max(maxy, y); }
    if (v.y > 0.f) { minx = min(minx, x + 1); maxx = max(maxx, x + 1); miny = min(miny, y); maxy = max(maxy, y); }
    if (v.z > 0.f) { minx = min(minx, x + 2); maxx = max(maxx, x + 2); miny = min(miny, y); maxy = max(maxy, y); }
    if (v.w > 0.f) { minx = min(minx, x + 3); maxx = max(maxx, x + 3); miny = min(miny, y); maxy = max(maxy, y); }
  }
  sminx[t] = minx; sminy[t] = miny; smaxx[t] = maxx; smaxy[t] = maxy;
  __syncthreads();
  for (int s = 128; s > 0; s >>= 1) {
    if (t < s) {
      sminx[t] = min(sminx[t], sminx[t + s]);
      sminy[t] = min(sminy[t], sminy[t + s]);
      smaxx[t] = max(smaxx[t], smaxx[t + s]);
      smaxy[t] = max(smaxy[t], smaxy[t + s]);
    }
    __syncthreads();
  }
  bool ne = smaxx[0] >= 0;
  if (t == 0) {
    float4 b;
    if (ne) b = make_float4((float)sminx[0], (float)sminy[0], (float)(smaxx[0] + 1), (float)(smaxy[0] + 1));
    else    b = make_float4(0.f, 0.f, (float)FW, (float)FH);  // argmax-of-all-false semantics
    boxes[n] = b;
  }
  if (t < NCLS) {
    float sc;
    if (ne) {
      float lg = cls[n * NCLS1 + t];
      sc = 1.0f / (1.0f + expf(-lg));
    } else {
      sc = -1.0f;
    }
    u32 o = ord32_r3(sc);
    u32 i = (u32)(n * NCLS + t);
    keys[i] = ((u64)o << 32) | (u64)(0xFFFFFFFFu - i);  // lower index -> larger key on ties
    atomicAdd(&hist[o >> 16], 1u);
  }
}

// ---------------- C: histogram bin of the 1000th largest key (uint4 loads) --------
__global__ void r6_thresh(const u32* __restrict__ hist, u32* __restrict__ cnts) {
  __shared__ u32 s[1024];
  int t = threadIdx.x;
  const uint4* hp = (const uint4*)(hist) + t * 16;
  u32 sum = 0;
  #pragma unroll
  for (int b = 0; b < 16; b++) {
    uint4 v = hp[b];
    sum += v.x + v.y + v.z + v.w;
  }
  s[t] = sum;
  __syncthreads();
  for (int off = 1; off < 1024; off <<= 1) {
    u32 v = s[t];
    u32 o = (t + off < 1024) ? s[t + off] : 0u;
    __syncthreads();
    s[t] = v + o;
    __syncthreads();
  }
  u32 sufnext = (t < 1023) ? s[t + 1] : 0u;
  if (s[t] >= (u32)KCAND && sufnext < (u32)KCAND) {
    u32 run = sufnext;
    u32 B = (u32)(t * 64);
    for (int b = 63; b >= 0; b--) {
      run += hist[t * 64 + b];
      if (run >= (u32)KCAND) { B = (u32)(t * 64 + b); break; }
    }
    cnts[1] = B;
  }
}

// ---------------- D: collect (wave-aggregated atomic) ----------------
__global__ void r5_collect(const u64* __restrict__ keys, const u32* __restrict__ cnts,
                           u64* __restrict__ collect, u32* __restrict__ counter) {
  int i = blockIdx.x * 256 + threadIdx.x;
  u32 B = cnts[1];
  bool pass = false;
  u64 k = 0ull;
  if (i < NC) {
    k = keys[i];
    pass = ((u32)(k >> 48) >= B);
  }
  u64 m = __ballot(pass);
  int lane = threadIdx.x & 63;
  u32 base = 0u;
  if (lane == 0 && m) base = atomicAdd(counter, (u32)__popcll(m));
  base = __shfl(base, 0, 64);
  if (pass) {
    u32 pos = base + (u32)__popcll(m & ((1ull << lane) - 1ull));
    if (pos < CAP) collect[pos] = k;
  }
}

// ---------------- E: exact stable rank, 16 blocks x 256 --------
__global__ void r5_rank(const u64* __restrict__ collect, const u32* __restrict__ cnts,
                        const float4* __restrict__ boxes,
                        int* __restrict__ clab, int* __restrict__ cfeat,
                        float* __restrict__ cscore, float4* __restrict__ cbox) {
  __shared__ u64 sk[CAP];
  int M = min((int)cnts[0], CAP);
  int t = threadIdx.x;
  for (int j = t; j < M; j += 256) sk[j] = collect[j];
  __syncthreads();
  int j = blockIdx.x * 256 + t;   // 16*256 = 4096 = CAP covers all M
  if (j < M) {
    u64 my = sk[j];
    int r = 0;
    for (int k = 0; k < M; k++) r += (sk[k] > my) ? 1 : 0;
    if (r < KCAND) {
      u32 idx = 0xFFFFFFFFu - (u32)(my & 0xFFFFFFFFull);
      int n = (int)idx / NCLS, c = (int)idx - n * NCLS;
      clab[r] = c;
      cfeat[r] = n;
      cscore[r] = unord32_r3((u32)(my >> 32));
      float4 b = boxes[n];
      float off = (float)c * 201.0f;  // label * (max(fH,fW)+1) on all 4 coords
      cbox[r] = make_float4(b.x + off, b.y + off, b.z + off, b.w + off);
    }
  }
}

// ---------------- F: IoU > thr bitmask rows, TRANSPOSED [word][row] layout --------
__global__ void r7_iou(const float4* __restrict__ cbox, u64* __restrict__ rowT) {
  __shared__ float4 sb[KCAND];
  int t = threadIdx.x;
  for (int j = t; j < KCAND; j += 256) sb[j] = cbox[j];
  __syncthreads();
  int w = t >> 6, lane = t & 63;
  int i = blockIdx.x * 4 + w;     // 256 blocks -> rows 0..1023 (rows >=1000 write 0)
  float4 bi = make_float4(0.f, 0.f, 0.f, 0.f);
  float ai = 0.f;
  if (i < KCAND) { bi = sb[i]; ai = (bi.z - bi.x) * (bi.w - bi.y); }
  for (int ch = 0; ch < 16; ch++) {
    int j = ch * 64 + lane;
    bool pred = false;
    if (i < KCAND && j < KCAND && j > i) {
      float4 bj = sb[j];
      float aj = (bj.z - bj.x) * (bj.w - bj.y);
      float ix1 = fmaxf(bi.x, bj.x), iy1 = fmaxf(bi.y, bj.y);
      float ix2 = fminf(bi.z, bj.z), iy2 = fminf(bi.w, bj.w);
      float inter = fmaxf(ix2 - ix1, 0.f) * fmaxf(iy2 - iy1, 0.f);
      float uni = ai + aj - inter;
      float iou = inter / fmaxf(uni, 1e-9f);
      pred = iou > 0.65f;
    }
    u64 m = __ballot(pred);
    if (lane == 0) rowT[(size_t)ch * 1024 + i] = m;
  }
}

// ---------------- G: greedy NMS scan, wave-parallel propagation + selection -------
__global__ void r7_nms_sel(const u64* __restrict__ rowT, const float* __restrict__ cscore,
                           const int* __restrict__ clab, const int* __restrict__ cfeat,
                           float* __restrict__ out, int* __restrict__ selfeat) {
  __shared__ u64 sup[16];
  __shared__ u64 keep[16];
  __shared__ u64 sel[16];
  __shared__ u32 pre[17];
  int t = threadIdx.x;
  int wv = t >> 6, lane = t & 63;
  if (t < 16) sup[t] = 0ull;
  __syncthreads();
  for (int c = 0; c < 16; c++) {
    u64 row = 0ull;
    if (wv > c) row = rowT[(size_t)wv * 1024 + c * 64 + lane];
    if (wv == 0) {
      u64 r = rowT[(size_t)c * 1024 + c * 64 + lane];  // diag word, coalesced
      u64 s = sup[c];
      u64 k = 0ull;
      #pragma unroll
      for (int b = 0; b < 64; b++) {
        u64 rb = __shfl(r, b, 64);   // constant b -> v_readlane
        if (!((s >> b) & 1ull)) { s |= rb; k |= (1ull << b); }
      }
      if (lane == 0) keep[c] = k;
    }
    __syncthreads();
    if (wv > c) {
      u64 kk = keep[c];
      u64 acc = ((kk >> lane) & 1ull) ? row : 0ull;
      #pragma unroll
      for (int off = 32; off >= 1; off >>= 1) acc |= __shfl_xor(acc, off, 64);
      if (lane == 0) sup[wv] |= acc;
    }
    __syncthreads();
  }
  {
    bool s = false;
    if (t < KCAND) {
      bool kp = ((keep[t >> 6] >> (t & 63)) & 1ull) != 0ull;
      s = kp && (cscore[t] >= 0.f);
    }
    u64 m = __ballot(s);
    if (lane == 0) sel[wv] = m;
  }
  __syncthreads();
  if (t == 0) {
    u32 acc = 0;
    #pragma unroll
    for (int c = 0; c < 16; c++) { pre[c] = acc; acc += (u32)__popcll(sel[c]); }
    pre[16] = acc;
  }
  __syncthreads();
  u32 nkept = pre[16];
  if (t < KCAND) {
    int j = t;
    u64 w = sel[j >> 6];
    bool s = ((w >> (j & 63)) & 1ull) != 0ull;
    u32 below = pre[j >> 6] + (u32)__popcll(w & ((1ull << (j & 63)) - 1ull));
    u32 r = s ? below : (nkept + (u32)j - below);
    if (r < MAXSEG) {
      out[r] = (float)clab[j];
      out[OUT_SCORE_OFF + r] = s ? cscore[j] : NEG_BIG;
      out[OUT_BATCH_OFF + r] = 0.0f;
      selfeat[r] = cfeat[j];
    }
  }
}

// ---------------- R: MULTI-ROW gather resize (8 rows/block, weights amortized) ----
// Measured structure data: weights-per-4-outputs gather = 181-208us; r10 (weights
// per 64 outputs, LDS+2 barriers) = 110us with warm compute 52.6us. This variant
// amortizes per-thread x-weights over 32 outputs (2.5 B/output) AND keeps the
// barrier-free streaming store pattern (stores from the first iteration) so the
// 419 MB HBM drain overlaps compute. img loads hit L1 (same 3 cols, ~3 distinct
// input rows per block). Identical fma/mul/PICK sequence -> bit-identical output.
__global__ void __launch_bounds__(256) r14_resize(const float* __restrict__ seg,
                                                  const int* __restrict__ selfeat,
                                                  const float4* __restrict__ wtab,
                                                  float* __restrict__ outm) {
  int t = threadIdx.x;
  int yb = blockIdx.x * RPB;     // 128 blocks x RPB rows = 1024 rows
  int slot = blockIdx.y;
  int feat = selfeat[slot];
  const float* img = seg + (size_t)feat * PIX;
  // per-thread x weights: loaded ONCE for RPB*4 = 32 outputs
  float4 wxa = wtab[t * 4], wxb = wtab[t * 4 + 1],
         wxc = wtab[t * 4 + 2], wxd = wtab[t * 4 + 3];
  int c0 = (int)wxa.z;                      // leftmost tap of this thread
  int c1 = min(c0 + 1, FW - 1);
  int c2 = min(c0 + 2, FW - 1);
  float* obase = outm + (size_t)slot * 1048576 + (size_t)yb * 1024 + t * 4;
  #pragma unroll
  for (int r = 0; r < RPB; ++r) {
    float4 wy = wtab[yb + r];    // uniform across block -> scalar load
    const float* r0 = img + (int)wy.z * FW;
    const float* r1 = img + (int)wy.w * FW;
    float wy0 = wy.x, wy1 = wy.y;
    // 6 deduped loads (L1-hot across rows: same cols, <=3 distinct input rows)
    float a0 = r0[c0], a1 = r0[c1], a2 = r0[c2];
    float b0 = r1[c0], b1 = r1[c1], b2 = r1[c2];
    // H contraction per distinct column — identical op order to previous rounds
    float h0 = __fmaf_rn(wy1, b0, __fmul_rn(wy0, a0));
    float h1 = __fmaf_rn(wy1, b1, __fmul_rn(wy0, a1));
    float h2 = __fmaf_rn(wy1, b2, __fmul_rn(wy0, a2));
    // branchless tap select by (index - c0) in {0,1,2}
    #define PICK(x) ((x) == c0 ? h0 : ((x) == c0 + 1 ? h1 : h2))
    float va = __fmaf_rn(wxa.y, PICK((int)wxa.w), __fmul_rn(wxa.x, h0));
    float vb = __fmaf_rn(wxb.y, PICK((int)wxb.w), __fmul_rn(wxb.x, PICK((int)wxb.z)));
    float vc = __fmaf_rn(wxc.y, PICK((int)wxc.w), __fmul_rn(wxc.x, PICK((int)wxc.z)));
    float vd = __fmaf_rn(wxd.y, PICK((int)wxd.w), __fmul_rn(wxd.x, PICK((int)wxd.z)));
    #undef PICK
    vf4 res;
    res.x = (va > 0.0f) ? 1.0f : 0.0f;
    res.y = (vb > 0.0f) ? 1.0f : 0.0f;
    res.z = (vc > 0.0f) ? 1.0f : 0.0f;
    res.w = (vd > 0.0f) ? 1.0f : 0.0f;
    *(vf4*)(obase + (size_t)r * 1024) = res;
  }
}

extern "C" void kernel_launch(void* const* d_in, const int* in_sizes, int n_in,
                              void* d_out, int out_size, void* d_ws, size_t ws_size,
                              hipStream_t stream) {
  const float* cls = (const float*)d_in[0];  // (300,81)
  const float* seg = (const float*)d_in[1];  // (300,200,200)
  float* out = (float*)d_out;
  char* ws = (char*)d_ws;

  u32* hist      = (u32*)(ws + WS_HIST);
  u64* keys      = (u64*)(ws + WS_KEYS);
  u64* collect   = (u64*)(ws + WS_COLLECT);
  u32* cnts      = (u32*)(ws + WS_CNT);
  float4* boxes  = (float4*)(ws + WS_BOXES);
  int* clab      = (int*)(ws + WS_CLAB);
  int* cfeat     = (int*)(ws + WS_CFEAT);
  float* cscore  = (float*)(ws + WS_CSCORE);
  float4* cbox   = (float4*)(ws + WS_CBOX);
  u64* rowT      = (u64*)(ws + WS_ROWBITS);
  int* selfeat   = (int*)(ws + WS_SELFEAT);
  float4* wtab   = (float4*)(ws + WS_WTAB);

  r13_init<<<dim3(NBINS / 256), dim3(256), 0, stream>>>(hist, cnts, wtab);
  r5_boxes<<<dim3(NF), dim3(256), 0, stream>>>(seg, cls, boxes, keys, hist);
  r6_thresh<<<dim3(1), dim3(1024), 0, stream>>>(hist, cnts);
  r5_collect<<<dim3((NC + 255) / 256), dim3(256), 0, stream>>>(keys, cnts, collect, &cnts[0]);
  r5_rank<<<dim3(16), dim3(256), 0, stream>>>(collect, cnts, boxes, clab, cfeat, cscore, cbox);
  r7_iou<<<dim3(256), dim3(256), 0, stream>>>(cbox, rowT);
  r7_nms_sel<<<dim3(1), dim3(1024), 0, stream>>>(rowT, cscore, clab, cfeat, out, selfeat);
  r14_resize<<<dim3(1024 / RPB, MAXSEG), dim3(256), 0, stream>>>(seg, selfeat, wtab, out + OUT_MASK_OFF);
}

// Round 16
// 550.818 us; speedup vs baseline: 2.5949x; 1.0380x over previous
//
#include <hip/hip_runtime.h>
#include <cstdint>
#include <cstddef>

typedef unsigned int u32;
typedef unsigned long long u64;
typedef float vf4 __attribute__((ext_vector_type(4)));

#define NF 300
#define NCLS 80
#define NCLS1 81
#define FH 200
#define FW 200
#define PIX 40000
#define NC 24000
#define KCAND 1000
#define CAP 4096
#define NBINS 65536
#define MAXSEG 100
#define OUT_MASK_OFF 100
#define OUT_SCORE_OFF 104857700
#define OUT_BATCH_OFF 104857800
#define NEG_BIG -3.3895313892515355e38f  /* finite sentinel, != -inf */
#define RYC 16   /* output rows per resize block */

// workspace byte offsets
#define WS_HIST      0u        // 65536*4
#define WS_KEYS      262144u   // 24000*8
#define WS_COLLECT   454144u   // 4096*8
#define WS_CNT       486912u   // 4*4
#define WS_BOXES     486928u   // 300*16 (16B aligned)
#define WS_CLAB      496928u
#define WS_CFEAT     500928u
#define WS_CSCORE    504928u
#define WS_CBOX      508928u   // 1000*16 (16B aligned)
#define WS_ROWBITS   524928u   // 16*1024*8 TRANSPOSED: word ch, row i -> [ch*1024+i]
#define WS_SELFEAT   656128u   // 100*4

__device__ __forceinline__ u32 ord32_r3(float f) {
  u32 b = __float_as_uint(f);
  return (b & 0x80000000u) ? ~b : (b | 0x80000000u);
}
__device__ __forceinline__ float unord32_r3(u32 o) {
  u32 b = (o & 0x80000000u) ? (o & 0x7FFFFFFFu) : ~o;
  return __uint_as_float(b);
}

// Exact bilinear weight for output index i (1024 -> 200, same both axes).
__device__ __forceinline__ float4 wcalc_r4(int i) {
  float s = __fsub_rn(__fmul_rn((float)i + 0.5f, 0.1953125f), 0.5f);
  int j0 = (int)floorf(s);
  int j1 = j0 + 1;
  float w0 = fmaxf(0.f, __fsub_rn(1.f, fabsf(__fsub_rn(s, (float)j0))));
  float w1 = fmaxf(0.f, __fsub_rn(1.f, fabsf(__fsub_rn(s, (float)j1))));
  bool in0 = (j0 >= 0) && (j0 < FH);
  bool in1 = (j1 >= 0) && (j1 < FH);
  float tot = __fadd_rn(in0 ? w0 : 0.f, in1 ? w1 : 0.f);
  float w0n = in0 ? (w0 / tot) : 0.f;   // IEEE div
  float w1n = in1 ? (w1 / tot) : 0.f;
  return make_float4(w0n, w1n, (float)max(j0, 0), (float)min(j1, FH - 1));
}

// ---------------- A: zero hist + counters ----------------
__global__ void r5_init(u32* __restrict__ hist, u32* __restrict__ cnts) {
  int i = blockIdx.x * 256 + threadIdx.x;   // grid covers 65536
  hist[i] = 0u;
  if (i < 4) cnts[i] = 0u;
}

// ---------------- B: per-mask bbox + fused sigmoid scores/keys + global hist ------
__global__ void r5_boxes(const float* __restrict__ seg, const float* __restrict__ cls,
                         float4* __restrict__ boxes, u64* __restrict__ keys,
                         u32* __restrict__ hist) {
  __shared__ int sminx[256], sminy[256], smaxx[256], smaxy[256];
  int n = blockIdx.x, t = threadIdx.x;
  const float4* img = (const float4*)(seg + (size_t)n * PIX);
  int minx = FW, miny = FH, maxx = -1, maxy = -1;
  for (int q = t; q < PIX / 4; q += 256) {
    float4 v = img[q];
    int p = q * 4;
    int y = p / FW;
    int x = p - y * FW;
    if (v.x > 0.f) { minx = min(minx, x);     maxx = max(maxx, x);     miny = min(miny, y); maxy = max(maxy, y); }
    if (v.y > 0.f) { minx = min(minx, x + 1); maxx = max(maxx, x + 1); miny = min(miny, y); maxy = max(maxy, y); }
    if (v.z > 0.f) { minx = min(minx, x + 2); maxx = max(maxx, x + 2); miny = min(miny, y); maxy = max(maxy, y); }
    if (v.w > 0.f) { minx = min(minx, x + 3); maxx = max(maxx, x + 3); miny = min(miny, y); maxy = max(maxy, y); }
  }
  sminx[t] = minx; sminy[t] = miny; smaxx[t] = maxx; smaxy[t] = maxy;
  __syncthreads();
  for (int s = 128; s > 0; s >>= 1) {
    if (t < s) {
      sminx[t] = min(sminx[t], sminx[t + s]);
      sminy[t] = min(sminy[t], sminy[t + s]);
      smaxx[t] = max(smaxx[t], smaxx[t + s]);
      smaxy[t] = max(smaxy[t], smaxy[t + s]);
    }
    __syncthreads();
  }
  bool ne = smaxx[0] >= 0;
  if (t == 0) {
    float4 b;
    if (ne) b = make_float4((float)sminx[0], (float)sminy[0], (float)(smaxx[0] + 1), (float)(smaxy[0] + 1));
    else    b = make_float4(0.f, 0.f, (float)FW, (float)FH);  // argmax-of-all-false semantics
    boxes[n] = b;
  }
  if (t < NCLS) {
    float sc;
    if (ne) {
      float lg = cls[n * NCLS1 + t];
      sc = 1.0f / (1.0f + expf(-lg));
    } else {
      sc = -1.0f;
    }
    u32 o = ord32_r3(sc);
    u32 i = (u32)(n * NCLS + t);
    keys[i] = ((u64)o << 32) | (u64)(0xFFFFFFFFu - i);  // lower index -> larger key on ties
    atomicAdd(&hist[o >> 16], 1u);
  }
}

// ---------------- C: histogram bin of the 1000th largest key (uint4 loads) --------
__global__ void r6_thresh(const u32* __restrict__ hist, u32* __restrict__ cnts) {
  __shared__ u32 s[1024];
  int t = threadIdx.x;
  const uint4* hp = (const uint4*)(hist) + t * 16;
  u32 sum = 0;
  #pragma unroll
  for (int b = 0; b < 16; b++) {
    uint4 v = hp[b];
    sum += v.x + v.y + v.z + v.w;
  }
  s[t] = sum;
  __syncthreads();
  for (int off = 1; off < 1024; off <<= 1) {
    u32 v = s[t];
    u32 o = (t + off < 1024) ? s[t + off] : 0u;
    __syncthreads();
    s[t] = v + o;
    __syncthreads();
  }
  u32 sufnext = (t < 1023) ? s[t + 1] : 0u;
  if (s[t] >= (u32)KCAND && sufnext < (u32)KCAND) {
    u32 run = sufnext;
    u32 B = (u32)(t * 64);
    for (int b = 63; b >= 0; b--) {
      run += hist[t * 64 + b];
      if (run >= (u32)KCAND) { B = (u32)(t * 64 + b); break; }
    }
    cnts[1] = B;
  }
}

// ---------------- D: collect (wave-aggregated atomic) ----------------
__global__ void r5_collect(const u64* __restrict__ keys, const u32* __restrict__ cnts,
                           u64* __restrict__ collect, u32* __restrict__ counter) {
  int i = blockIdx.x * 256 + threadIdx.x;
  u32 B = cnts[1];
  bool pass = false;
  u64 k = 0ull;
  if (i < NC) {
    k = keys[i];
    pass = ((u32)(k >> 48) >= B);
  }
  u64 m = __ballot(pass);
  int lane = threadIdx.x & 63;
  u32 base = 0u;
  if (lane == 0 && m) base = atomicAdd(counter, (u32)__popcll(m));
  base = __shfl(base, 0, 64);
  if (pass) {
    u32 pos = base + (u32)__popcll(m & ((1ull << lane) - 1ull));
    if (pos < CAP) collect[pos] = k;
  }
}

// ---------------- E: exact stable rank, 16 blocks x 256 --------
__global__ void r5_rank(const u64* __restrict__ collect, const u32* __restrict__ cnts,
                        const float4* __restrict__ boxes,
                        int* __restrict__ clab, int* __restrict__ cfeat,
                        float* __restrict__ cscore, float4* __restrict__ cbox) {
  __shared__ u64 sk[CAP];
  int M = min((int)cnts[0], CAP);
  int t = threadIdx.x;
  for (int j = t; j < M; j += 256) sk[j] = collect[j];
  __syncthreads();
  int j = blockIdx.x * 256 + t;   // 16*256 = 4096 = CAP covers all M
  if (j < M) {
    u64 my = sk[j];
    int r = 0;
    for (int k = 0; k < M; k++) r += (sk[k] > my) ? 1 : 0;
    if (r < KCAND) {
      u32 idx = 0xFFFFFFFFu - (u32)(my & 0xFFFFFFFFull);
      int n = (int)idx / NCLS, c = (int)idx - n * NCLS;
      clab[r] = c;
      cfeat[r] = n;
      cscore[r] = unord32_r3((u32)(my >> 32));
      float4 b = boxes[n];
      float off = (float)c * 201.0f;  // label * (max(fH,fW)+1) on all 4 coords
      cbox[r] = make_float4(b.x + off, b.y + off, b.z + off, b.w + off);
    }
  }
}

// ---------------- F: IoU > thr bitmask rows, TRANSPOSED [word][row] layout --------
__global__ void r7_iou(const float4* __restrict__ cbox, u64* __restrict__ rowT) {
  __shared__ float4 sb[KCAND];
  int t = threadIdx.x;
  for (int j = t; j < KCAND; j += 256) sb[j] = cbox[j];
  __syncthreads();
  int w = t >> 6, lane = t & 63;
  int i = blockIdx.x * 4 + w;     // 256 blocks -> rows 0..1023 (rows >=1000 write 0)
  float4 bi = make_float4(0.f, 0.f, 0.f, 0.f);
  float ai = 0.f;
  if (i < KCAND) { bi = sb[i]; ai = (bi.z - bi.x) * (bi.w - bi.y); }
  for (int ch = 0; ch < 16; ch++) {
    int j = ch * 64 + lane;
    bool pred = false;
    if (i < KCAND && j < KCAND && j > i) {
      float4 bj = sb[j];
      float aj = (bj.z - bj.x) * (bj.w - bj.y);
      float ix1 = fmaxf(bi.x, bj.x), iy1 = fmaxf(bi.y, bj.y);
      float ix2 = fminf(bi.z, bj.z), iy2 = fminf(bi.w, bj.w);
      float inter = fmaxf(ix2 - ix1, 0.f) * fmaxf(iy2 - iy1, 0.f);
      float uni = ai + aj - inter;
      float iou = inter / fmaxf(uni, 1e-9f);
      pred = iou > 0.65f;
    }
    u64 m = __ballot(pred);
    if (lane == 0) rowT[(size_t)ch * 1024 + i] = m;
  }
}

// ---------------- G: greedy NMS scan, wave-parallel propagation + selection -------
__global__ void r7_nms_sel(const u64* __restrict__ rowT, const float* __restrict__ cscore,
                           const int* __restrict__ clab, const int* __restrict__ cfeat,
                           float* __restrict__ out, int* __restrict__ selfeat) {
  __shared__ u64 sup[16];
  __shared__ u64 keep[16];
  __shared__ u64 sel[16];
  __shared__ u32 pre[17];
  int t = threadIdx.x;
  int wv = t >> 6, lane = t & 63;
  if (t < 16) sup[t] = 0ull;
  __syncthreads();
  for (int c = 0; c < 16; c++) {
    u64 row = 0ull;
    if (wv > c) row = rowT[(size_t)wv * 1024 + c * 64 + lane];
    if (wv == 0) {
      u64 r = rowT[(size_t)c * 1024 + c * 64 + lane];  // diag word, coalesced
      u64 s = sup[c];
      u64 k = 0ull;
      #pragma unroll
      for (int b = 0; b < 64; b++) {
        u64 rb = __shfl(r, b, 64);   // constant b -> v_readlane
        if (!((s >> b) & 1ull)) { s |= rb; k |= (1ull << b); }
      }
      if (lane == 0) keep[c] = k;
    }
    __syncthreads();
    if (wv > c) {
      u64 kk = keep[c];
      u64 acc = ((kk >> lane) & 1ull) ? row : 0ull;
      #pragma unroll
      for (int off = 32; off >= 1; off >>= 1) acc |= __shfl_xor(acc, off, 64);
      if (lane == 0) sup[wv] |= acc;
    }
    __syncthreads();
  }
  {
    bool s = false;
    if (t < KCAND) {
      bool kp = ((keep[t >> 6] >> (t & 63)) & 1ull) != 0ull;
      s = kp && (cscore[t] >= 0.f);
    }
    u64 m = __ballot(s);
    if (lane == 0) sel[wv] = m;
  }
  __syncthreads();
  if (t == 0) {
    u32 acc = 0;
    #pragma unroll
    for (int c = 0; c < 16; c++) { pre[c] = acc; acc += (u32)__popcll(sel[c]); }
    pre[16] = acc;
  }
  __syncthreads();
  u32 nkept = pre[16];
  if (t < KCAND) {
    int j = t;
    u64 w = sel[j >> 6];
    bool s = ((w >> (j & 63)) & 1ull) != 0ull;
    u32 below = pre[j >> 6] + (u32)__popcll(w & ((1ull << (j & 63)) - 1ull));
    u32 r = s ? below : (nkept + (u32)j - below);
    if (r < MAXSEG) {
      out[r] = (float)clab[j];
      out[OUT_SCORE_OFF + r] = s ? cscore[j] : NEG_BIG;
      out[OUT_BATCH_OFF + r] = 0.0f;
      selfeat[r] = cfeat[j];
    }
  }
}

// ---------------- R: bilinear resize, H-then-W staged (proven best: 110us) --------
// Final config: the measured-best of four structures (110 vs 124/181/208).
// Stage th[r][x] once per block; each output = 2 LDS reads + mul + fma.
// Identical op order to all variants -> bit-identical output.
__global__ void __launch_bounds__(256, 4) r10_resize(const float* __restrict__ seg,
                                                     const int* __restrict__ selfeat,
                                                     float* __restrict__ outm) {
  __shared__ float srow[6][FW];      // <=5 input rows + slack
  __shared__ float th[RYC][FW];      // H-interpolated rows (12.8 KB)
  __shared__ float4 swy[RYC];        // y-weights, srow-relative indices
  int t = threadIdx.x;
  int yb = blockIdx.x * RYC, slot = blockIdx.y;
  int feat = selfeat[slot];
  const float* img = seg + (size_t)feat * PIX;
  float4 wxa = wcalc_r4(t * 4), wxb = wcalc_r4(t * 4 + 1),
         wxc = wcalc_r4(t * 4 + 2), wxd = wcalc_r4(t * 4 + 3);
  int ylo = (int)wcalc_r4(yb).z;               // clamped lo row of first output row
  int yhi = (int)wcalc_r4(yb + RYC - 1).w;     // clamped hi row of last output row
  int nr = yhi - ylo + 1;                      // <= 5
  if (t < RYC) {
    float4 wy = wcalc_r4(yb + t);
    swy[t] = make_float4(wy.x, wy.y, (float)((int)wy.z - ylo), (float)((int)wy.w - ylo));
  }
  for (int e = t; e < nr * FW; e += 256) {
    int rr = e / FW, cc = e - rr * FW;
    srow[rr][cc] = img[(ylo + rr) * FW + cc];
  }
  __syncthreads();
  // H pass: one interpolated row per output row, staged in LDS
  #pragma unroll
  for (int r = 0; r < RYC; ++r) {
    if (t < FW) {
      float4 wy = swy[r];
      th[r][t] = __fmaf_rn(wy.y, srow[(int)wy.w][t], __fmul_rn(wy.x, srow[(int)wy.z][t]));
    }
  }
  __syncthreads();
  // W pass: 2 LDS reads + mul + fma per output, then threshold + float4 store
  int xa0 = (int)wxa.z, xa1 = (int)wxa.w;
  int xb0 = (int)wxb.z, xb1 = (int)wxb.w;
  int xc0 = (int)wxc.z, xc1 = (int)wxc.w;
  int xd0 = (int)wxd.z, xd1 = (int)wxd.w;
  float* obase = outm + (size_t)slot * 1048576 + (size_t)yb * 1024 + t * 4;
  #pragma unroll
  for (int r = 0; r < RYC; ++r) {
    const float* thr = th[r];
    float va = __fmaf_rn(wxa.y, thr[xa1], __fmul_rn(wxa.x, thr[xa0]));
    float vb = __fmaf_rn(wxb.y, thr[xb1], __fmul_rn(wxb.x, thr[xb0]));
    float vc = __fmaf_rn(wxc.y, thr[xc1], __fmul_rn(wxc.x, thr[xc0]));
    float vd = __fmaf_rn(wxd.y, thr[xd1], __fmul_rn(wxd.x, thr[xd0]));
    vf4 res;
    res.x = (va > 0.0f) ? 1.0f : 0.0f;
    res.y = (vb > 0.0f) ? 1.0f : 0.0f;
    res.z = (vc > 0.0f) ? 1.0f : 0.0f;
    res.w = (vd > 0.0f) ? 1.0f : 0.0f;
    *(vf4*)(obase + (size_t)r * 1024) = res;   // plain store
  }
}

extern "C" void kernel_launch(void* const* d_in, const int* in_sizes, int n_in,
                              void* d_out, int out_size, void* d_ws, size_t ws_size,
                              hipStream_t stream) {
  const float* cls = (const float*)d_in[0];  // (300,81)
  const float* seg = (const float*)d_in[1];  // (300,200,200)
  float* out = (float*)d_out;
  char* ws = (char*)d_ws;

  u32* hist      = (u32*)(ws + WS_HIST);
  u64* keys      = (u64*)(ws + WS_KEYS);
  u64* collect   = (u64*)(ws + WS_COLLECT);
  u32* cnts      = (u32*)(ws + WS_CNT);
  float4* boxes  = (float4*)(ws + WS_BOXES);
  int* clab      = (int*)(ws + WS_CLAB);
  int* cfeat     = (int*)(ws + WS_CFEAT);
  float* cscore  = (float*)(ws + WS_CSCORE);
  float4* cbox   = (float4*)(ws + WS_CBOX);
  u64* rowT      = (u64*)(ws + WS_ROWBITS);
  int* selfeat   = (int*)(ws + WS_SELFEAT);

  r5_init<<<dim3(NBINS / 256), dim3(256), 0, stream>>>(hist, cnts);
  r5_boxes<<<dim3(NF), dim3(256), 0, stream>>>(seg, cls, boxes, keys, hist);
  r6_thresh<<<dim3(1), dim3(1024), 0, stream>>>(hist, cnts);
  r5_collect<<<dim3((NC + 255) / 256), dim3(256), 0, stream>>>(keys, cnts, collect, &cnts[0]);
  r5_rank<<<dim3(16), dim3(256), 0, stream>>>(collect, cnts, boxes, clab, cfeat, cscore, cbox);
  r7_iou<<<dim3(256), dim3(256), 0, stream>>>(cbox, rowT);
  r7_nms_sel<<<dim3(1), dim3(1024), 0, stream>>>(rowT, cscore, clab, cfeat, out, selfeat);
  r10_resize<<<dim3(1024 / RYC, MAXSEG), dim3(256), 0, stream>>>(seg, selfeat, out + OUT_MASK_OFF);
}